// Round 7
// baseline (192.535 us; speedup 1.0000x reference)
//
#include <hip/hip_runtime.h>
#include <hip/hip_bf16.h>

#define DIM 1024
#define NH 16
#define HD 64
#define BB 2
#define SS 2048
#define MROWS (BB * SS)   // 4096
#define SCALE 0.03125f    // 1024^-0.5
#define SC_LOG2E 0.04508422002778011f  // SCALE * log2(e)

typedef unsigned short u16;
typedef unsigned int u32;
typedef __attribute__((ext_vector_type(8))) short short8;
typedef __attribute__((ext_vector_type(4))) float f32x4;
typedef __attribute__((ext_vector_type(2))) unsigned int u32x2;

#if __has_builtin(__builtin_amdgcn_exp2f)
#define EXP2(x) __builtin_amdgcn_exp2f(x)
#else
#define EXP2(x) __builtin_exp2f(x)
#endif

__device__ __forceinline__ u16 f2bf(float f) {
  union { float f; u32 u; } v; v.f = f;
  return (u16)((v.u + 0x7fffu + ((v.u >> 16) & 1u)) >> 16);
}

__device__ __forceinline__ u32 pack2bf(float a, float b) {
  union { __hip_bfloat162 h; u32 u; } cv;
  cv.h = __float22bfloat162_rn(make_float2(a, b));
  return cv.u;
}

// permlane swaps: dst high row <-> src low row (row=32 / row=16 lanes)
__device__ __forceinline__ void plswap32(u32& a, u32& b) {
#if __has_builtin(__builtin_amdgcn_permlane32_swap)
  u32x2 t = __builtin_amdgcn_permlane32_swap(a, b, false, false);
  a = t[0]; b = t[1];
#else
  asm("v_permlane32_swap_b32 %0, %1" : "+v"(a), "+v"(b));
#endif
}
__device__ __forceinline__ void plswap16(u32& a, u32& b) {
#if __has_builtin(__builtin_amdgcn_permlane16_swap)
  u32x2 t = __builtin_amdgcn_permlane16_swap(a, b, false, false);
  a = t[0]; b = t[1];
#else
  asm("v_permlane16_swap_b32 %0, %1" : "+v"(a), "+v"(b));
#endif
}

__device__ __forceinline__ void async16(const u16* g, u16* l) {
  __builtin_amdgcn_global_load_lds(
      (const __attribute__((address_space(1))) void*)(const void*)g,
      (__attribute__((address_space(3))) void*)(void*)l, 16, 0, 0);
}

__device__ __forceinline__ short8 ld8(const u16* p) { return *(const short8*)p; }

// ---------------- fp32 -> bf16 convert (vectorized) ----------------
__global__ void cvt_kernel(const float* __restrict__ in, u16* __restrict__ out, int n4) {
  int i = blockIdx.x * blockDim.x + threadIdx.x;
  if (i < n4) {
    float4 v = ((const float4*)in)[i];
    u32 lo = (u32)f2bf(v.x) | ((u32)f2bf(v.y) << 16);
    u32 hi = (u32)f2bf(v.z) | ((u32)f2bf(v.w) << 16);
    ((uint2*)out)[i] = make_uint2(lo, hi);
  }
}

// ------- transpose + convert: in fp32 [R][C] -> out bf16 [C][R] -------
__global__ void tconv_kernel(const float* __restrict__ in, u16* __restrict__ out, int R, int C) {
  __shared__ u16 t[64 * 65];
  int c0 = blockIdx.x * 64, r0 = blockIdx.y * 64;
  #pragma unroll
  for (int i = 0; i < 16; i++) {
    int j = i * 256 + threadIdx.x;
    int rr = j >> 6, cc = j & 63;
    t[rr * 65 + cc] = f2bf(in[(size_t)(r0 + rr) * C + c0 + cc]);
  }
  __syncthreads();
  #pragma unroll
  for (int i = 0; i < 16; i++) {
    int j = i * 256 + threadIdx.x;
    int oc = j >> 6, orr = j & 63;
    out[(size_t)(c0 + oc) * R + r0 + orr] = t[orr * 65 + oc];
  }
}

// ---- bf16 GEMM, BM=128 x BN=64, swizzled LDS, prefetch-dbuf, XCD swizzle ----
// C[M,N] = A[M,K] @ Bt[N,K]^T + bias.
// Occupancy: 24KB LDS dbuf + 32-reg acc -> 4 blocks/CU (16 waves/CU).
// T2 bank-conflict fix (both-sides, rule #21): staging lane pre-swizzles the
// GLOBAL 16B-chunk index gchunk = (l&3) ^ ((l>>3)&3) (LDS dest stays linear),
// so LDS slot c' of row rr holds global chunk c'^((rr>>1)&3); fragment reads
// use slot q ^ ((r>>1)&3). Even/odd rows each spread over all 4 bank-quads ->
// 2 lanes/bank = conflict-free.
// T3-min 2-phase: STAGE(k0+32) into alternate buffer BEFORE compute of k0.
// T1: bijective XCD remap (nwg % 8 == 0); each XCD walks whole A row-panels.
// MODE 0: QKV epilogue -> Q,K cols to qk2 [4096][2048] (Q pre-scaled by
//         SC_LOG2E), V cols packed-transposed to vT [b][h][d][s].
//         (BN=64 divides the 192-col head group evenly: each 64-block is
//          entirely Q, entirely K, or entirely V.)
// MODE 1: plain fp32 output [M][N].
template <int MODE, int NXB>
__global__ __launch_bounds__(256, 4) void gemm_n64(
    const u16* __restrict__ A, const u16* __restrict__ Bt,
    const float* __restrict__ bias, void* __restrict__ C,
    u16* __restrict__ vT, int M, int N, int K) {
  __shared__ __align__(16) u16 smem[12288];  // 24KB: 2 x (As 8KB + Bs 4KB)
  const int tid = threadIdx.x;
  const int w = tid >> 6, l = tid & 63;
  const int r = l & 15, q = l >> 4;
  const int nwg = gridDim.x;
  const int cpx = nwg >> 3;
  const int lin = blockIdx.x;
  const int swz = (lin & 7) * cpx + (lin >> 3);
  const int m0 = (swz / NXB) * 128, n0 = (swz % NXB) * 64;
  const int qm = (w & 1) * 64, qn = (w >> 1) * 32;

  // staging: lane l -> row w*16+(l>>2), LDS chunk-slot l&3, global chunk:
  const int gchunk = (l & 3) ^ ((l >> 3) & 3);
  const size_t aoff = (size_t)(m0 + w * 16 + (l >> 2)) * K + (size_t)gchunk * 8;
  const size_t boff = (size_t)(n0 + w * 16 + (l >> 2)) * K + (size_t)gchunk * 8;
  const int soff = (w * 64 + l) * 8;   // == (w*16+(l>>2))*32 + (l&3)*8
  const int xq = (r >> 1) & 3;         // read-side chunk XOR (row bits 1-2)

#define NSTAGE(K0, BASE) do {                                                    \
    u16* As_ = (BASE); u16* Bs_ = As_ + 4096;                                    \
    async16(A + aoff + (K0), As_ + soff);                                        \
    async16(A + aoff + (size_t)64 * K + (K0), As_ + soff + 2048);                \
    async16(Bt + boff + (K0), Bs_ + soff);                                       \
  } while (0)

  f32x4 acc[4][2] = {};
  NSTAGE(0, smem);
  __syncthreads();
  for (int k0 = 0; k0 < K; k0 += 32) {
    u16* As = smem + ((k0 >> 5) & 1) * 6144;
    u16* Bs = As + 4096;
    if (k0 + 32 < K) NSTAGE(k0 + 32, smem + ((((k0 >> 5) & 1) ^ 1) * 6144));
    short8 af[4], bfr[2];
    #pragma unroll
    for (int i = 0; i < 4; i++)
      af[i] = ld8(&As[(qm + i * 16 + r) * 32 + (q ^ xq) * 8]);
    #pragma unroll
    for (int j = 0; j < 2; j++)
      bfr[j] = ld8(&Bs[(qn + j * 16 + r) * 32 + (q ^ xq) * 8]);
    #pragma unroll
    for (int i = 0; i < 4; i++)
      #pragma unroll
      for (int j = 0; j < 2; j++)
        acc[i][j] = __builtin_amdgcn_mfma_f32_16x16x32_bf16(af[i], bfr[j], acc[i][j], 0, 0, 0);
    __syncthreads();   // drains prefetch vmcnt + all waves done with this buf
  }
#undef NSTAGE
  // epilogue: C layout col = lane&15, row = quad*4 + reg
  #pragma unroll
  for (int i = 0; i < 4; i++) {
    int ro = m0 + qm + i * 16 + q * 4;
    #pragma unroll
    for (int j = 0; j < 2; j++) {
      int col = n0 + qn + j * 16 + r;
      float bv = bias[col];
      float v0 = acc[i][j][0] + bv, v1 = acc[i][j][1] + bv;
      float v2 = acc[i][j][2] + bv, v3 = acc[i][j][3] + bv;
      if (MODE == 1) {
        float* out = (float*)C;
        out[(size_t)(ro + 0) * N + col] = v0;
        out[(size_t)(ro + 1) * N + col] = v1;
        out[(size_t)(ro + 2) * N + col] = v2;
        out[(size_t)(ro + 3) * N + col] = v3;
      } else {
        int h = col / 192, wi = col - h * 192;
        if (wi >= 128) {
          // V: packed-transposed store, vT[((b*NH+h)*HD + d)*SS + s], 4 s's contiguous
          int bb = ro >> 11, s = ro & 2047, d = wi - 128;
          uint2 pk = make_uint2(pack2bf(v0, v1), pack2bf(v2, v3));
          *(uint2*)&vT[((size_t)((bb * NH + h) * HD + d)) * SS + s] = pk;
        } else {
          u16* qk2 = (u16*)C;
          const float sc = (wi < 64) ? SC_LOG2E : 1.0f;  // pre-scale Q only
          qk2[(size_t)(ro + 0) * 2048 + h * 128 + wi] = f2bf(v0 * sc);
          qk2[(size_t)(ro + 1) * 2048 + h * 128 + wi] = f2bf(v1 * sc);
          qk2[(size_t)(ro + 2) * 2048 + h * 128 + wi] = f2bf(v2 * sc);
          qk2[(size_t)(ro + 3) * 2048 + h * 128 + wi] = f2bf(v3 * sc);
        }
      }
    }
  }
}

// ------------------------- fused attention v6 -------------------------
// (unchanged from R4/R6 passing version)
__global__ __launch_bounds__(512, 4) void attn6_kernel(
    const u16* __restrict__ qk2, const u16* __restrict__ vT,
    u16* __restrict__ attno) {
  __shared__ __align__(16) u16 smem[32768];  // 65536B: buf0{Ks,Vs} | buf1{Ks,Vs}
  const int tid = threadIdx.x;
  const int w = tid >> 6, l = tid & 63;
  const int r = l & 15, q = l >> 4;
  const int wq = w & 3, ws = w >> 2;
  // XCD-aware bijective swizzle of (q-block, h, b)
  const int lin = blockIdx.x + 16 * (blockIdx.y + 16 * blockIdx.z);  // 0..511
  const int k8 = lin & 7, jj = lin >> 3;
  const int bh = ((jj >> 4) << 3) + k8;      // 0..31, constant per XCD group
  const int h = bh & 15, b = bh >> 4;
  const int q0 = (jj & 15) * 128;

  const u16* qb = qk2 + (size_t)b * SS * 2048;
  const u16* kB = qb + h * 128 + 64;
  const u16* vB = vT + (size_t)((b * NH + h) * HD) * SS;

  // Q fragments (B-operand): rows q0+wq*32+i*16+r, k = kq*32+q*8 (pre-scaled)
  short8 qf[2][2];
  #pragma unroll
  for (int i = 0; i < 2; i++)
    #pragma unroll
    for (int kq = 0; kq < 2; kq++)
      qf[i][kq] = ld8(qb + (size_t)(q0 + wq * 32 + i * 16 + r) * 2048 + h * 128 + kq * 32 + q * 8);

  // staging lane constants
  const int klrow = l >> 3;                 // K: row within 8-row group
  const int kchunk = (l & 7) ^ klrow;       // K: swizzled global 16B-chunk
  const int vlrow = l >> 4;                 // V: row within 4-row group
  const int vslot = l & 15;                 // V: LDS slot

#define STAGE(KV0, DST) do {                                                     \
    u16* Kd_ = (DST); u16* Vd_ = Kd_ + 8192;                                     \
    _Pragma("unroll")                                                            \
    for (int tt = 0; tt < 2; tt++) {                                             \
      int g = w * 2 + tt;                                                        \
      async16(kB + (size_t)((KV0) + g * 8 + klrow) * 2048 + kchunk * 8,          \
              &Kd_[g * 512 + l * 8]);                                            \
    }                                                                            \
    _Pragma("unroll")                                                            \
    for (int tt = 0; tt < 2; tt++) {                                             \
      int g = w * 2 + tt;                                                        \
      int d_ = g * 4 + vlrow;                                                    \
      int c_ = vslot ^ (d_ & 15);                                                \
      async16(vB + (size_t)d_ * SS + (KV0) + c_ * 8, &Vd_[g * 512 + l * 8]);     \
    }                                                                            \
  } while (0)

#define CONV(ks) do {                                                            \
    _Pragma("unroll")                                                            \
    for (int i = 0; i < 2; i++) {                                                \
      f32x4 sa = sacc[(ks) * 2][i], sb = sacc[(ks) * 2 + 1][i];                  \
      u32 A0 = pack2bf(EXP2(sa[0]), EXP2(sa[1]));                                \
      u32 A1 = pack2bf(EXP2(sa[2]), EXP2(sa[3]));                                \
      u32 B0 = pack2bf(EXP2(sb[0]), EXP2(sb[1]));                                \
      u32 B1 = pack2bf(EXP2(sb[2]), EXP2(sb[3]));                                \
      plswap32(A0, B0);                                                          \
      plswap32(A1, B1);                                                          \
      plswap16(A0, B0);                                                          \
      plswap16(A1, B1);                                                          \
      union { short8 s8; u32 u[4]; } pk;                                         \
      pk.u[0] = A0; pk.u[1] = A1; pk.u[2] = B0; pk.u[3] = B1;                    \
      pa[ks][i] = pk.s8;                                                         \
    }                                                                            \
  } while (0)

#define QKT(j2) do {                                                             \
    const u16* krow = &Ks[(ws * 64 + (j2) * 16 + r) * 64];                       \
    short8 a0 = ld8(krow + ((q ^ (r & 7)) * 8));                                 \
    short8 a1 = ld8(krow + (((4 + q) ^ (r & 7)) * 8));                           \
    __builtin_amdgcn_s_setprio(1);                                               \
    _Pragma("unroll")                                                            \
    for (int i = 0; i < 2; i++) {                                                \
      sacc[j2][i] = __builtin_amdgcn_mfma_f32_16x16x32_bf16(a0, qf[i][0], sacc[j2][i], 0, 0, 0); \
      sacc[j2][i] = __builtin_amdgcn_mfma_f32_16x16x32_bf16(a1, qf[i][1], sacc[j2][i], 0, 0, 0); \
    }                                                                            \
    __builtin_amdgcn_s_setprio(0);                                               \
  } while (0)

#define PV(ks) do {                                                              \
    __builtin_amdgcn_s_setprio(1);                                               \
    den[0] = __builtin_amdgcn_mfma_f32_16x16x32_bf16(pa[ks][0], vone, den[0], 0, 0, 0); \
    den[1] = __builtin_amdgcn_mfma_f32_16x16x32_bf16(pa[ks][1], vone, den[1], 0, 0, 0); \
    _Pragma("unroll")                                                            \
    for (int dj = 0; dj < 4; dj++) {                                             \
      short8 vb = ld8(&Vs[(dj * 16 + r) * 128 + (((ws * 8 + (ks) * 4 + q) ^ r) * 8)]); \
      oacc[0][dj] = __builtin_amdgcn_mfma_f32_16x16x32_bf16(pa[ks][0], vb, oacc[0][dj], 0, 0, 0); \
      oacc[1][dj] = __builtin_amdgcn_mfma_f32_16x16x32_bf16(pa[ks][1], vb, oacc[1][dj], 0, 0, 0); \
    }                                                                            \
    __builtin_amdgcn_s_setprio(0);                                               \
  } while (0)

  const short8 vone = {0x3F80, 0x3F80, 0x3F80, 0x3F80, 0x3F80, 0x3F80, 0x3F80, 0x3F80};
  f32x4 oacc[2][4] = {};
  f32x4 den[2] = {};

  STAGE(0, smem);            // prologue: tile 0 -> buf 0
  __syncthreads();

  for (int t = 0; t < 16; ++t) {
    const int cur = t & 1;
    u16* Ks = smem + cur * 16384;
    u16* Vs = Ks + 8192;
    if (t < 15) STAGE((t + 1) * 128, smem + (cur ^ 1) * 16384);  // prefetch next

    f32x4 sacc[4][2] = {};
    short8 pa[2][2];
    // pipelined order: every VALU cluster sits between independent MFMA clusters
    QKT(0); QKT(1);
    CONV(0);               // overlaps QKT(2,3) below
    QKT(2); QKT(3);
    PV(0);                 // overlaps CONV(1) below
    CONV(1);
    PV(1);
    __syncthreads();   // drains our prefetch (vmcnt 0) + all waves done with buf
  }
#undef STAGE
#undef CONV
#undef QKT
#undef PV

  // ---- cross-wave reduction between s-halves (LDS reused as f32 scratch) ----
  float* part = (float*)smem;            // [4 wq][2 half][32 col][36] f32
  float* dnf  = part + 8 * 32 * 36;      // [2 ws][4 wq][32] f32
  const int ho = 1 - ws;
  {
    const int wbase = (wq * 2 + ho) * 32;   // region owned by the partner
    #pragma unroll
    for (int i = 0; i < 2; i++) {
      if (ws == 0) {
        *(f32x4*)&part[(wbase + r) * 36 + i * 16 + q * 4]      = oacc[i][2];
        *(f32x4*)&part[(wbase + 16 + r) * 36 + i * 16 + q * 4] = oacc[i][3];
      } else {
        *(f32x4*)&part[(wbase + r) * 36 + i * 16 + q * 4]      = oacc[i][0];
        *(f32x4*)&part[(wbase + 16 + r) * 36 + i * 16 + q * 4] = oacc[i][1];
      }
      if (r == 0)
        *(f32x4*)&dnf[(ws * 4 + wq) * 32 + i * 16 + q * 4] = den[i];
    }
  }
  __syncthreads();
  {
    const int rbase = (wq * 2 + ws) * 32;   // our own region (partner wrote it)
    #pragma unroll
    for (int i = 0; i < 2; i++) {
      f32x4 dt = *(f32x4*)&dnf[(ho * 4 + wq) * 32 + i * 16 + q * 4] + den[i];
      f32x4 oa, ob;
      if (ws == 0) { oa = oacc[i][0]; ob = oacc[i][1]; }
      else         { oa = oacc[i][2]; ob = oacc[i][3]; }
      oa += *(f32x4*)&part[(rbase + r) * 36 + i * 16 + q * 4];
      ob += *(f32x4*)&part[(rbase + 16 + r) * 36 + i * 16 + q * 4];
      #pragma unroll
      for (int e = 0; e < 4; e++) {
        float di = 1.f / dt[e];
        int row = q0 + wq * 32 + i * 16 + q * 4 + e;
        u16* o = &attno[(size_t)(b * SS + row) * DIM + h * HD + ws * 32 + r];
        o[0]  = f2bf(oa[e] * di);
        o[16] = f2bf(ob[e] * di);
      }
    }
  }
}

extern "C" void kernel_launch(void* const* d_in, const int* in_sizes, int n_in,
                              void* d_out, int out_size, void* d_ws, size_t ws_size,
                              hipStream_t stream) {
  const float* x      = (const float*)d_in[0];
  const float* w_qkv  = (const float*)d_in[1];
  const float* b_qkv  = (const float*)d_in[2];
  const float* w_proj = (const float*)d_in[3];
  const float* b_proj = (const float*)d_in[4];
  float* out = (float*)d_out;
  char* ws = (char*)d_ws;
  // workspace layout (48 MB total)
  u16* xb     = (u16*)(ws);                       // [4096,1024]       8 MB
  u16* wqkvT  = (u16*)(ws + ((size_t)8  << 20));  // [3072,1024]       6 MB
  u16* wprojT = (u16*)(ws + ((size_t)14 << 20));  // [1024,1024]       2 MB
  u16* qk2    = (u16*)(ws + ((size_t)16 << 20));  // [4096,2048] Q,K  16 MB
  u16* attno  = (u16*)(ws + ((size_t)32 << 20));  // [4096,1024]       8 MB
  u16* vT     = (u16*)(ws + ((size_t)40 << 20));  // [2,16,64,2048]    8 MB

  cvt_kernel<<<4096, 256, 0, stream>>>(x, xb, MROWS * DIM / 4);
  tconv_kernel<<<dim3(48, 16), 256, 0, stream>>>(w_qkv, wqkvT, DIM, 3 * DIM);
  tconv_kernel<<<dim3(16, 16), 256, 0, stream>>>(w_proj, wprojT, DIM, DIM);
  // QKV: 32 row-panels x 48 col-panels = 1536 blocks (1536 % 8 == 0)
  gemm_n64<0, 48><<<1536, 256, 0, stream>>>(xb, wqkvT, b_qkv, qk2, vT, MROWS, 3 * DIM, DIM);
  attn6_kernel<<<dim3(16, NH, BB), 512, 0, stream>>>(qk2, vT, attno);
  // proj: 32 x 16 = 512 blocks (4 blocks/CU)
  gemm_n64<1, 16><<<512, 256, 0, stream>>>(attno, wprojT, b_proj, out, nullptr, MROWS, DIM, DIM);
}

// Round 9
// 177.018 us; speedup vs baseline: 1.0877x; 1.0877x over previous
//
#include <hip/hip_runtime.h>
#include <hip/hip_bf16.h>

#define DIM 1024
#define NH 16
#define HD 64
#define BB 2
#define SS 2048
#define MROWS (BB * SS)   // 4096
#define SCALE 0.03125f    // 1024^-0.5
#define SC_LOG2E 0.04508422002778011f  // SCALE * log2(e)

typedef unsigned short u16;
typedef unsigned int u32;
typedef __attribute__((ext_vector_type(8))) short short8;
typedef __attribute__((ext_vector_type(4))) float f32x4;
typedef __attribute__((ext_vector_type(2))) unsigned int u32x2;

#if __has_builtin(__builtin_amdgcn_exp2f)
#define EXP2(x) __builtin_amdgcn_exp2f(x)
#else
#define EXP2(x) __builtin_exp2f(x)
#endif

__device__ __forceinline__ u16 f2bf(float f) {
  union { float f; u32 u; } v; v.f = f;
  return (u16)((v.u + 0x7fffu + ((v.u >> 16) & 1u)) >> 16);
}

__device__ __forceinline__ u32 pack2bf(float a, float b) {
  union { __hip_bfloat162 h; u32 u; } cv;
  cv.h = __float22bfloat162_rn(make_float2(a, b));
  return cv.u;
}

// permlane swaps: dst high row <-> src low row (row=32 / row=16 lanes)
__device__ __forceinline__ void plswap32(u32& a, u32& b) {
#if __has_builtin(__builtin_amdgcn_permlane32_swap)
  u32x2 t = __builtin_amdgcn_permlane32_swap(a, b, false, false);
  a = t[0]; b = t[1];
#else
  asm("v_permlane32_swap_b32 %0, %1" : "+v"(a), "+v"(b));
#endif
}
__device__ __forceinline__ void plswap16(u32& a, u32& b) {
#if __has_builtin(__builtin_amdgcn_permlane16_swap)
  u32x2 t = __builtin_amdgcn_permlane16_swap(a, b, false, false);
  a = t[0]; b = t[1];
#else
  asm("v_permlane16_swap_b32 %0, %1" : "+v"(a), "+v"(b));
#endif
}

__device__ __forceinline__ void async16(const u16* g, u16* l) {
  __builtin_amdgcn_global_load_lds(
      (const __attribute__((address_space(1))) void*)(const void*)g,
      (__attribute__((address_space(3))) void*)(void*)l, 16, 0, 0);
}

__device__ __forceinline__ short8 ld8(const u16* p) { return *(const short8*)p; }

// ---------------- fp32 -> bf16 convert (vectorized) ----------------
__global__ void cvt_kernel(const float* __restrict__ in, u16* __restrict__ out, int n4) {
  int i = blockIdx.x * blockDim.x + threadIdx.x;
  if (i < n4) {
    float4 v = ((const float4*)in)[i];
    u32 lo = (u32)f2bf(v.x) | ((u32)f2bf(v.y) << 16);
    u32 hi = (u32)f2bf(v.z) | ((u32)f2bf(v.w) << 16);
    ((uint2*)out)[i] = make_uint2(lo, hi);
  }
}

// ------- transpose + convert: in fp32 [R][C] -> out bf16 [C][R] -------
__global__ void tconv_kernel(const float* __restrict__ in, u16* __restrict__ out, int R, int C) {
  __shared__ u16 t[64 * 65];
  int c0 = blockIdx.x * 64, r0 = blockIdx.y * 64;
  #pragma unroll
  for (int i = 0; i < 16; i++) {
    int j = i * 256 + threadIdx.x;
    int rr = j >> 6, cc = j & 63;
    t[rr * 65 + cc] = f2bf(in[(size_t)(r0 + rr) * C + c0 + cc]);
  }
  __syncthreads();
  #pragma unroll
  for (int i = 0; i < 16; i++) {
    int j = i * 256 + threadIdx.x;
    int oc = j >> 6, orr = j & 63;
    out[(size_t)(c0 + oc) * R + r0 + orr] = t[orr * 65 + oc];
  }
}

// ---- bf16 GEMM, BM=128 x BN={128,64}, BK=64: C = A @ Bt^T + bias ----
// BK=64 halves the vmcnt(0)+barrier drains vs BK=32 (16 K-steps at K=1024),
// doubling MFMA per drain — attacks the measured barrier-bound regime
// (R6/R7: MfmaUtil ~20%, no saturated pipe, drains dominate).
// LDS: dbuf 2x(16KB A + BN*128B B): BN=128 -> 64KB (2 blocks/CU);
//      BN=64 -> 48KB (3 blocks/CU).
// T2 chunk swizzle (both-sides, rule #21): rows are 8x16B chunks; staging lane
// pre-swizzles GLOBAL chunk gc=(l&7)^(l>>3) with linear LDS dest, so LDS slot s
// of row rr holds global chunk s^(rr&7); reads use slot (kq*4+q)^(r&7) ->
// 16 lanes spread 8 slots x 2 = 2 lanes/bank (free).
// T3-min 2-phase prefetch; T1 bijective XCD remap (nwg % 8 == 0).
// Wave->output map: 2x2 wave grid; wave row stride 64 (qm), wave COLUMN
// stride BN/2 (qn) since each wave-col owns JN=BN/32 j-frags = BN/2 cols.
// (R8 bug: qn used BN/4 -> cols 96-127 unwritten + 32-63 raced. Fixed.)
// MODE 0 epilogue: Q,K -> qk2 (Q pre-scaled by SC_LOG2E), V -> vT transposed.
// MODE 1: plain fp32 output.
template <int MODE, int BN, int NXB>
__global__ __launch_bounds__(256, (BN == 128 ? 2 : 3)) void gemm_bk64(
    const u16* __restrict__ A, const u16* __restrict__ Bt,
    const float* __restrict__ bias, void* __restrict__ C,
    u16* __restrict__ vT, int M, int N, int K) {
  constexpr int JN = BN / 32;              // B-frags / wave (4 or 2)
  constexpr int BTI = BN / 32;             // B staging iters (BN/4 rows / 8)
  constexpr int BUF = 8192 + BN * 64;      // u16 per buffer
  __shared__ __align__(16) u16 smem[2 * BUF];
  const int tid = threadIdx.x;
  const int w = tid >> 6, l = tid & 63;
  const int r = l & 15, q = l >> 4;
  const int nwg = gridDim.x;
  const int cpx = nwg >> 3;
  const int lin = blockIdx.x;
  const int swz = (lin & 7) * cpx + (lin >> 3);
  const int m0 = (swz / NXB) * 128, n0 = (swz % NXB) * BN;
  const int qm = (w & 1) * 64, qn = (w >> 1) * (BN / 2);

  // staging: lane l -> row-sub (l>>3), LDS chunk-slot l&7, global chunk:
  const int gc = (l & 7) ^ (l >> 3);
  const size_t aoffb = (size_t)(m0 + w * 32 + (l >> 3)) * K + (size_t)gc * 8;
  const size_t boffb = (size_t)(n0 + w * (BN / 4) + (l >> 3)) * K + (size_t)gc * 8;
  const int xs = r & 7;                    // read-side row XOR

#define GSTAGE(K0, BASE) do {                                                    \
    u16* As_ = (BASE); u16* Bs_ = As_ + 8192;                                    \
    _Pragma("unroll")                                                            \
    for (int t = 0; t < 4; t++)                                                  \
      async16(A + aoffb + (size_t)t * 8 * K + (K0), As_ + w * 2048 + t * 512 + l * 8); \
    _Pragma("unroll")                                                            \
    for (int t = 0; t < BTI; t++)                                                \
      async16(Bt + boffb + (size_t)t * 8 * K + (K0), Bs_ + w * (BN * 16) + t * 512 + l * 8); \
  } while (0)

  f32x4 acc[4][JN] = {};
  GSTAGE(0, smem);
  __syncthreads();
  for (int k0 = 0; k0 < K; k0 += 64) {
    u16* As = smem + ((k0 >> 6) & 1) * BUF;
    u16* Bs = As + 8192;
    if (k0 + 64 < K) GSTAGE(k0 + 64, smem + ((((k0 >> 6) & 1) ^ 1) * BUF));
    short8 af[2][4], bfr[2][JN];
    #pragma unroll
    for (int kq = 0; kq < 2; kq++) {
      #pragma unroll
      for (int i = 0; i < 4; i++)
        af[kq][i] = ld8(&As[(qm + i * 16 + r) * 64 + (((kq * 4 + q) ^ xs) * 8)]);
      #pragma unroll
      for (int j = 0; j < JN; j++)
        bfr[kq][j] = ld8(&Bs[(qn + j * 16 + r) * 64 + (((kq * 4 + q) ^ xs) * 8)]);
    }
    #pragma unroll
    for (int kq = 0; kq < 2; kq++)
      #pragma unroll
      for (int i = 0; i < 4; i++)
        #pragma unroll
        for (int j = 0; j < JN; j++)
          acc[i][j] = __builtin_amdgcn_mfma_f32_16x16x32_bf16(af[kq][i], bfr[kq][j], acc[i][j], 0, 0, 0);
    __syncthreads();   // drains prefetch vmcnt + all waves done with this buf
  }
#undef GSTAGE
  // epilogue: C layout col = lane&15, row = quad*4 + reg
  #pragma unroll
  for (int i = 0; i < 4; i++) {
    int ro = m0 + qm + i * 16 + q * 4;
    #pragma unroll
    for (int j = 0; j < JN; j++) {
      int col = n0 + qn + j * 16 + r;
      float bv = bias[col];
      float v0 = acc[i][j][0] + bv, v1 = acc[i][j][1] + bv;
      float v2 = acc[i][j][2] + bv, v3 = acc[i][j][3] + bv;
      if (MODE == 1) {
        float* out = (float*)C;
        out[(size_t)(ro + 0) * N + col] = v0;
        out[(size_t)(ro + 1) * N + col] = v1;
        out[(size_t)(ro + 2) * N + col] = v2;
        out[(size_t)(ro + 3) * N + col] = v3;
      } else {
        int h = col / 192, wi = col - h * 192;
        if (wi >= 128) {
          // V: packed-transposed store, vT[((b*NH+h)*HD + d)*SS + s], 4 s's contiguous
          int bb = ro >> 11, s = ro & 2047, d = wi - 128;
          uint2 pk = make_uint2(pack2bf(v0, v1), pack2bf(v2, v3));
          *(uint2*)&vT[((size_t)((bb * NH + h) * HD + d)) * SS + s] = pk;
        } else {
          u16* qk2 = (u16*)C;
          const float sc = (wi < 64) ? SC_LOG2E : 1.0f;  // pre-scale Q only
          qk2[(size_t)(ro + 0) * 2048 + h * 128 + wi] = f2bf(v0 * sc);
          qk2[(size_t)(ro + 1) * 2048 + h * 128 + wi] = f2bf(v1 * sc);
          qk2[(size_t)(ro + 2) * 2048 + h * 128 + wi] = f2bf(v2 * sc);
          qk2[(size_t)(ro + 3) * 2048 + h * 128 + wi] = f2bf(v3 * sc);
        }
      }
    }
  }
}

// ------------------------- fused attention v6 -------------------------
// (unchanged from R4/R6 passing version)
__global__ __launch_bounds__(512, 4) void attn6_kernel(
    const u16* __restrict__ qk2, const u16* __restrict__ vT,
    u16* __restrict__ attno) {
  __shared__ __align__(16) u16 smem[32768];  // 65536B: buf0{Ks,Vs} | buf1{Ks,Vs}
  const int tid = threadIdx.x;
  const int w = tid >> 6, l = tid & 63;
  const int r = l & 15, q = l >> 4;
  const int wq = w & 3, ws = w >> 2;
  // XCD-aware bijective swizzle of (q-block, h, b)
  const int lin = blockIdx.x + 16 * (blockIdx.y + 16 * blockIdx.z);  // 0..511
  const int k8 = lin & 7, jj = lin >> 3;
  const int bh = ((jj >> 4) << 3) + k8;      // 0..31, constant per XCD group
  const int h = bh & 15, b = bh >> 4;
  const int q0 = (jj & 15) * 128;

  const u16* qb = qk2 + (size_t)b * SS * 2048;
  const u16* kB = qb + h * 128 + 64;
  const u16* vB = vT + (size_t)((b * NH + h) * HD) * SS;

  // Q fragments (B-operand): rows q0+wq*32+i*16+r, k = kq*32+q*8 (pre-scaled)
  short8 qf[2][2];
  #pragma unroll
  for (int i = 0; i < 2; i++)
    #pragma unroll
    for (int kq = 0; kq < 2; kq++)
      qf[i][kq] = ld8(qb + (size_t)(q0 + wq * 32 + i * 16 + r) * 2048 + h * 128 + kq * 32 + q * 8);

  // staging lane constants
  const int klrow = l >> 3;                 // K: row within 8-row group
  const int kchunk = (l & 7) ^ klrow;       // K: swizzled global 16B-chunk
  const int vlrow = l >> 4;                 // V: row within 4-row group
  const int vslot = l & 15;                 // V: LDS slot

#define STAGE(KV0, DST) do {                                                     \
    u16* Kd_ = (DST); u16* Vd_ = Kd_ + 8192;                                     \
    _Pragma("unroll")                                                            \
    for (int tt = 0; tt < 2; tt++) {                                             \
      int g = w * 2 + tt;                                                        \
      async16(kB + (size_t)((KV0) + g * 8 + klrow) * 2048 + kchunk * 8,          \
              &Kd_[g * 512 + l * 8]);                                            \
    }                                                                            \
    _Pragma("unroll")                                                            \
    for (int tt = 0; tt < 2; tt++) {                                             \
      int g = w * 2 + tt;                                                        \
      int d_ = g * 4 + vlrow;                                                    \
      int c_ = vslot ^ (d_ & 15);                                                \
      async16(vB + (size_t)d_ * SS + (KV0) + c_ * 8, &Vd_[g * 512 + l * 8]);     \
    }                                                                            \
  } while (0)

#define CONV(ks) do {                                                            \
    _Pragma("unroll")                                                            \
    for (int i = 0; i < 2; i++) {                                                \
      f32x4 sa = sacc[(ks) * 2][i], sb = sacc[(ks) * 2 + 1][i];                  \
      u32 A0 = pack2bf(EXP2(sa[0]), EXP2(sa[1]));                                \
      u32 A1 = pack2bf(EXP2(sa[2]), EXP2(sa[3]));                                \
      u32 B0 = pack2bf(EXP2(sb[0]), EXP2(sb[1]));                                \
      u32 B1 = pack2bf(EXP2(sb[2]), EXP2(sb[3]));                                \
      plswap32(A0, B0);                                                          \
      plswap32(A1, B1);                                                          \
      plswap16(A0, B0);                                                          \
      plswap16(A1, B1);                                                          \
      union { short8 s8; u32 u[4]; } pk;                                         \
      pk.u[0] = A0; pk.u[1] = A1; pk.u[2] = B0; pk.u[3] = B1;                    \
      pa[ks][i] = pk.s8;                                                         \
    }                                                                            \
  } while (0)

#define QKT(j2) do {                                                             \
    const u16* krow = &Ks[(ws * 64 + (j2) * 16 + r) * 64];                       \
    short8 a0 = ld8(krow + ((q ^ (r & 7)) * 8));                                 \
    short8 a1 = ld8(krow + (((4 + q) ^ (r & 7)) * 8));                           \
    __builtin_amdgcn_s_setprio(1);                                               \
    _Pragma("unroll")                                                            \
    for (int i = 0; i < 2; i++) {                                                \
      sacc[j2][i] = __builtin_amdgcn_mfma_f32_16x16x32_bf16(a0, qf[i][0], sacc[j2][i], 0, 0, 0); \
      sacc[j2][i] = __builtin_amdgcn_mfma_f32_16x16x32_bf16(a1, qf[i][1], sacc[j2][i], 0, 0, 0); \
    }                                                                            \
    __builtin_amdgcn_s_setprio(0);                                               \
  } while (0)

#define PV(ks) do {                                                              \
    __builtin_amdgcn_s_setprio(1);                                               \
    den[0] = __builtin_amdgcn_mfma_f32_16x16x32_bf16(pa[ks][0], vone, den[0], 0, 0, 0); \
    den[1] = __builtin_amdgcn_mfma_f32_16x16x32_bf16(pa[ks][1], vone, den[1], 0, 0, 0); \
    _Pragma("unroll")                                                            \
    for (int dj = 0; dj < 4; dj++) {                                             \
      short8 vb = ld8(&Vs[(dj * 16 + r) * 128 + (((ws * 8 + (ks) * 4 + q) ^ r) * 8)]); \
      oacc[0][dj] = __builtin_amdgcn_mfma_f32_16x16x32_bf16(pa[ks][0], vb, oacc[0][dj], 0, 0, 0); \
      oacc[1][dj] = __builtin_amdgcn_mfma_f32_16x16x32_bf16(pa[ks][1], vb, oacc[1][dj], 0, 0, 0); \
    }                                                                            \
    __builtin_amdgcn_s_setprio(0);                                               \
  } while (0)

  const short8 vone = {0x3F80, 0x3F80, 0x3F80, 0x3F80, 0x3F80, 0x3F80, 0x3F80, 0x3F80};
  f32x4 oacc[2][4] = {};
  f32x4 den[2] = {};

  STAGE(0, smem);            // prologue: tile 0 -> buf 0
  __syncthreads();

  for (int t = 0; t < 16; ++t) {
    const int cur = t & 1;
    u16* Ks = smem + cur * 16384;
    u16* Vs = Ks + 8192;
    if (t < 15) STAGE((t + 1) * 128, smem + (cur ^ 1) * 16384);  // prefetch next

    f32x4 sacc[4][2] = {};
    short8 pa[2][2];
    // pipelined order: every VALU cluster sits between independent MFMA clusters
    QKT(0); QKT(1);
    CONV(0);               // overlaps QKT(2,3) below
    QKT(2); QKT(3);
    PV(0);                 // overlaps CONV(1) below
    CONV(1);
    PV(1);
    __syncthreads();   // drains our prefetch (vmcnt 0) + all waves done with buf
  }
#undef STAGE
#undef CONV
#undef QKT
#undef PV

  // ---- cross-wave reduction between s-halves (LDS reused as f32 scratch) ----
  float* part = (float*)smem;            // [4 wq][2 half][32 col][36] f32
  float* dnf  = part + 8 * 32 * 36;      // [2 ws][4 wq][32] f32
  const int ho = 1 - ws;
  {
    const int wbase = (wq * 2 + ho) * 32;   // region owned by the partner
    #pragma unroll
    for (int i = 0; i < 2; i++) {
      if (ws == 0) {
        *(f32x4*)&part[(wbase + r) * 36 + i * 16 + q * 4]      = oacc[i][2];
        *(f32x4*)&part[(wbase + 16 + r) * 36 + i * 16 + q * 4] = oacc[i][3];
      } else {
        *(f32x4*)&part[(wbase + r) * 36 + i * 16 + q * 4]      = oacc[i][0];
        *(f32x4*)&part[(wbase + 16 + r) * 36 + i * 16 + q * 4] = oacc[i][1];
      }
      if (r == 0)
        *(f32x4*)&dnf[(ws * 4 + wq) * 32 + i * 16 + q * 4] = den[i];
    }
  }
  __syncthreads();
  {
    const int rbase = (wq * 2 + ws) * 32;   // our own region (partner wrote it)
    #pragma unroll
    for (int i = 0; i < 2; i++) {
      f32x4 dt = *(f32x4*)&dnf[(ho * 4 + wq) * 32 + i * 16 + q * 4] + den[i];
      f32x4 oa, ob;
      if (ws == 0) { oa = oacc[i][0]; ob = oacc[i][1]; }
      else         { oa = oacc[i][2]; ob = oacc[i][3]; }
      oa += *(f32x4*)&part[(rbase + r) * 36 + i * 16 + q * 4];
      ob += *(f32x4*)&part[(rbase + 16 + r) * 36 + i * 16 + q * 4];
      #pragma unroll
      for (int e = 0; e < 4; e++) {
        float di = 1.f / dt[e];
        int row = q0 + wq * 32 + i * 16 + q * 4 + e;
        u16* o = &attno[(size_t)(b * SS + row) * DIM + h * HD + ws * 32 + r];
        o[0]  = f2bf(oa[e] * di);
        o[16] = f2bf(ob[e] * di);
      }
    }
  }
}

extern "C" void kernel_launch(void* const* d_in, const int* in_sizes, int n_in,
                              void* d_out, int out_size, void* d_ws, size_t ws_size,
                              hipStream_t stream) {
  const float* x      = (const float*)d_in[0];
  const float* w_qkv  = (const float*)d_in[1];
  const float* b_qkv  = (const float*)d_in[2];
  const float* w_proj = (const float*)d_in[3];
  const float* b_proj = (const float*)d_in[4];
  float* out = (float*)d_out;
  char* ws = (char*)d_ws;
  // workspace layout (48 MB total)
  u16* xb     = (u16*)(ws);                       // [4096,1024]       8 MB
  u16* wqkvT  = (u16*)(ws + ((size_t)8  << 20));  // [3072,1024]       6 MB
  u16* wprojT = (u16*)(ws + ((size_t)14 << 20));  // [1024,1024]       2 MB
  u16* qk2    = (u16*)(ws + ((size_t)16 << 20));  // [4096,2048] Q,K  16 MB
  u16* attno  = (u16*)(ws + ((size_t)32 << 20));  // [4096,1024]       8 MB
  u16* vT     = (u16*)(ws + ((size_t)40 << 20));  // [2,16,64,2048]    8 MB

  cvt_kernel<<<4096, 256, 0, stream>>>(x, xb, MROWS * DIM / 4);
  tconv_kernel<<<dim3(48, 16), 256, 0, stream>>>(w_qkv, wqkvT, DIM, 3 * DIM);
  tconv_kernel<<<dim3(16, 16), 256, 0, stream>>>(w_proj, wprojT, DIM, DIM);
  // QKV: 128x128 tiles, 32 row-panels x 24 col-panels = 768 blocks (%8==0)
  gemm_bk64<0, 128, 24><<<768, 256, 0, stream>>>(xb, wqkvT, b_qkv, qk2, vT, MROWS, 3 * DIM, DIM);
  attn6_kernel<<<dim3(16, NH, BB), 512, 0, stream>>>(qk2, vT, attno);
  // proj: 128x64 tiles, 32 x 16 = 512 blocks (3 blocks/CU)
  gemm_bk64<1, 64, 16><<<512, 256, 0, stream>>>(attno, wprojT, b_proj, out, nullptr, MROWS, DIM, DIM);
}